// Round 2
// baseline (233.668 us; speedup 1.0000x reference)
//
#include <hip/hip_runtime.h>

#define T_STEPS 256
#define HID 40
#define EPB 16
#define NTHR 512
#define RR 56              // row stride (shorts): [h(40) | pad(16)]; 112B = 28-dword stride -> 2-way max
#define PP (16 * RR)       // parity stride = 896 shorts
#define OL1 (2 * PP)       // L1 region offset = 1792 shorts
#define STOT (4 * PP)      // 3584 shorts = 7168 B

typedef __attribute__((ext_vector_type(8))) short bf16x8;
typedef __attribute__((ext_vector_type(4))) float f32x4;
typedef __attribute__((ext_vector_type(8))) float f32x8;
typedef __attribute__((ext_vector_type(4))) unsigned int u32x4;

__device__ __forceinline__ unsigned short bf16_rne(float v) {
    unsigned int x = __float_as_uint(v);
    unsigned int r = x + 0x7FFFu + ((x >> 16) & 1u);
    return (unsigned short)(r >> 16);
}
// single-instruction bf16 convert (RNE)
__device__ __forceinline__ unsigned short bf16_cvt(float v) {
    unsigned int r;
    asm("v_cvt_pk_bf16_f32 %0, %1, %2" : "=v"(r) : "v"(v), "v"(v));
    return (unsigned short)r;
}
// fast gates (r16-proven): v_exp_f32 = 2^x; v_rcp_f32 replaces IEEE divide
__device__ __forceinline__ float sigm(float v) {
    return __builtin_amdgcn_rcpf(1.0f + __builtin_amdgcn_exp2f(-1.4426950408889634f * v));
}
__device__ __forceinline__ float tanh_f(float v) {
    return 1.0f - 2.0f * __builtin_amdgcn_rcpf(__builtin_amdgcn_exp2f(2.8853900817779268f * v) + 1.0f);
}

#define MF(A_, B_, C_) C_ = __builtin_amdgcn_mfma_f32_16x16x32_bf16(A_, B_, C_, 0, 0, 0)
#define PINV(v) asm volatile("" : "+v"(v))

// A-frag over unified K-concat rows [h_self(40) | input(KX)] (r15-proven mapping).
// element at k = 32c + 8qrow + j: k<40 -> Whh[rh][k]; 40<=k<40+KX -> Wih[rx][k-40]; else 0.
__device__ bf16x8 afrag(const float* Whh, const float* Wih, int KX,
                        int rh, int rx, int c, int qrow) {
    bf16x8 f;
    #pragma unroll
    for (int j = 0; j < 8; ++j) f[j] = 0;
    #pragma unroll
    for (int j = 0; j < 8; ++j) {
        const int k = 32 * c + qrow * 8 + j;
        if (k < 40) {
            if (rh >= 0) f[j] = (short)bf16_rne(Whh[rh * 40 + k]);
        } else if (k < 40 + KX) {
            if (rx >= 0) f[j] = (short)bf16_rne(Wih[rx * KX + (k - 40)]);
        }
    }
    return f;
}

// r17 structure: 8 waves (one L0 + one L1 wave per SIMD). Waves 0-3 = L0 with
// tile counts (3,3,2,2); waves 4-7 = L1 with (3,3,2,2). Each wave shares its
// B-reads across all its tiles (LDS reads/step: 42 -> 20). x is loaded
// global->reg (4-deep prefetch) and cndmask-spliced into chunk-1 B lanes
// (qrow 1,2); L1 reads h0 straight out of L0's LDS region via per-lane
// concat addressing, so L0 writes h0 exactly once. Layer skew + ping-pong
// parity + 1 barrier/step retained from r13/r14.
__global__ __launch_bounds__(NTHR, 2)
void gru2_kernel(const float* __restrict__ x,
                 const float* __restrict__ Wih0, const float* __restrict__ Whh0,
                 const float* __restrict__ bih0, const float* __restrict__ bhh0,
                 const float* __restrict__ Wih1, const float* __restrict__ Whh1,
                 const float* __restrict__ bih1, const float* __restrict__ bhh1,
                 float* __restrict__ out)
{
    __shared__ __align__(16) unsigned short S[STOT];

    const int tid  = threadIdx.x;
    const int wid  = tid >> 6;     // 0..7
    const int l    = tid & 63;
    const int col  = l & 15;       // example within group / MFMA col
    const int qrow = l >> 4;
    const int ps   = (l & 15) & 3; // slot (0=r,1=z,2=nx,3=nh)
    const int pu   = (l & 15) >> 2;
    const int e0   = blockIdx.x * EPB;

    const bool isL1 = wid >= 4;
    const int  m    = isL1 ? wid - 4 : wid;
    const int  NTIL = (m < 2) ? 3 : 2;
    const int  Tb   = (m < 2) ? 3 * m : 6 + 2 * (m - 2);

    const float* Whh = isL1 ? Whh1 : Whh0;
    const float* Wih = isL1 ? Wih1 : Wih0;
    const float* bih = isL1 ? bih1 : bih0;
    const float* bhh = isL1 ? bhh1 : bhh0;
    const int KX = isL1 ? 40 : 16;

    // ---- A-frags (up to 3 tiles x 3 chunks) + biases ----
    bf16x8 ZF;
    #pragma unroll
    for (int j = 0; j < 8; ++j) ZF[j] = 0;
    bf16x8 F00=ZF,F01=ZF,F02=ZF, F10=ZF,F11=ZF,F12=ZF, F20=ZF,F21=ZF,F22=ZF;
    f32x4 BB0, BB1, BB2;
    {
#define RRX(u, RH, RX) \
        const int RH = (ps == 2) ? -1 : (ps == 0 ? (u) : ps == 1 ? 40 + (u) : 80 + (u)); \
        const int RX = (ps == 3) ? -1 : (ps == 0 ? (u) : ps == 1 ? 40 + (u) : 80 + (u));
        {
            const int u0 = 4 * (Tb + 0) + pu;
            RRX(u0, rh0, rx0);
            F00 = afrag(Whh, Wih, KX, rh0, rx0, 0, qrow);
            F01 = afrag(Whh, Wih, KX, rh0, rx0, 1, qrow);
            if (isL1) F02 = afrag(Whh, Wih, KX, rh0, rx0, 2, qrow);
        }
        {
            const int u1 = 4 * (Tb + 1) + pu;
            RRX(u1, rh1, rx1);
            F10 = afrag(Whh, Wih, KX, rh1, rx1, 0, qrow);
            F11 = afrag(Whh, Wih, KX, rh1, rx1, 1, qrow);
            if (isL1) F12 = afrag(Whh, Wih, KX, rh1, rx1, 2, qrow);
        }
        if (NTIL == 3) {
            const int u2 = 4 * (Tb + 2) + pu;
            RRX(u2, rh2, rx2);
            F20 = afrag(Whh, Wih, KX, rh2, rx2, 0, qrow);
            F21 = afrag(Whh, Wih, KX, rh2, rx2, 1, qrow);
            if (isL1) F22 = afrag(Whh, Wih, KX, rh2, rx2, 2, qrow);
        }
        const int uc0 = 4 * (Tb + 0) + qrow;
        const int uc1 = 4 * (Tb + 1) + qrow;
        BB0[0] = bih[uc0] + bhh[uc0];
        BB0[1] = bih[40 + uc0] + bhh[40 + uc0];
        BB0[2] = bih[80 + uc0];
        BB0[3] = bhh[80 + uc0];
        BB1[0] = bih[uc1] + bhh[uc1];
        BB1[1] = bih[40 + uc1] + bhh[40 + uc1];
        BB1[2] = bih[80 + uc1];
        BB1[3] = bhh[80 + uc1];
        if (NTIL == 3) {
            const int uc2 = 4 * (Tb + 2) + qrow;
            BB2[0] = bih[uc2] + bhh[uc2];
            BB2[1] = bih[40 + uc2] + bhh[40 + uc2];
            BB2[2] = bih[80 + uc2];
            BB2[3] = bhh[80 + uc2];
        } else {
            BB2[0] = BB2[1] = BB2[2] = BB2[3] = 0.f;
        }
    }
    PINV(F00); PINV(F01); PINV(F02);
    PINV(F10); PINV(F11); PINV(F12);
    PINV(F20); PINV(F21); PINV(F22);
    PINV(BB0); PINV(BB1); PINV(BB2);

    // ---- per-lane B-read addresses (shorts), one per chunk per parity ----
    // L0 rows: [h0(40)|pad]; chunk0 = h0[8q..], chunk1 = h0[32..39] broadcast
    // (qrow>0 lanes spliced from x regs / dead). L1 reads over concat
    // [h1(40) in own region | h0(40) in L0 region]; group g = 4c+qrow.
    int r0p0, r0p1, r1p0, r1p1, r2p0, r2p1;
    if (!isL1) {
        r0p0 = col * RR + 8 * qrow;  r0p1 = r0p0 + PP;
        r1p0 = col * RR + 32;        r1p1 = r1p0 + PP;
        r2p0 = 0;                    r2p1 = 0;
    } else {
        auto ga = [&](int g, int p) -> int {
            if (g < 5)  return OL1 + p * PP + col * RR + 8 * g;      // h1
            if (g < 10) return p * PP + col * RR + 8 * (g - 5);      // h0 (L0 region)
            return p * PP + col * RR;                                // dead lane (A=0)
        };
        r0p0 = ga(qrow, 0);     r0p1 = ga(qrow, 1);
        r1p0 = ga(4 + qrow, 0); r1p1 = ga(4 + qrow, 1);
        r2p0 = ga(8 + qrow, 0); r2p1 = ga(8 + qrow, 1);
    }
    // write offset (parity added at use): unit u = 4*Tb+qrow + 4*tt
    const int wof = (isL1 ? OL1 : 0) + col * RR + 4 * Tb + qrow;
    const bool usex = (qrow == 1) || (qrow == 2);
    unsigned short* Sb = &S[0];
    float hA0 = 0.f, hA1 = 0.f, hA2 = 0.f;

    // ---- zero LDS (initial h = 0; pads stay 0) ----
    for (int idx = tid; idx < STOT; idx += NTHR) Sb[idx] = 0;

    // ---- x prefetch: 4-deep ring in registers (L0 waves only) ----
    const float* xrow = x + (size_t)(e0 + col) * (T_STEPS * 16) + ((qrow == 2) ? 8 : 0);
    f32x8 XA, XB, XC, XD;
    #pragma unroll
    for (int j = 0; j < 8; ++j) { XA[j] = 0.f; XB[j] = 0.f; XC[j] = 0.f; XD[j] = 0.f; }
    if (!isL1) {
        XA = *(const f32x8*)(xrow);
        XB = *(const f32x8*)(xrow + 16);
        XC = *(const f32x8*)(xrow + 32);
        XD = *(const f32x8*)(xrow + 48);
    }
    __syncthreads();

#define GMATH(C, H) \
    const float r_ = sigm(C[0]); \
    const float z_ = sigm(C[1]); \
    const float n_ = tanh_f(C[2] + r_ * C[3]); \
    H = n_ + z_ * (H - n_);

#define BODY(RP, XQ) { \
    if (!isL1) { \
        const bf16x8 S0 = *(const bf16x8*)(Sb + r0p##RP); \
        bf16x8 S1 = *(const bf16x8*)(Sb + r1p##RP); \
        if (t < T_STEPS) { \
            unsigned int xw0, xw1, xw2, xw3; \
            asm("v_cvt_pk_bf16_f32 %0, %1, %2" : "=v"(xw0) : "v"(XQ[0]), "v"(XQ[1])); \
            asm("v_cvt_pk_bf16_f32 %0, %1, %2" : "=v"(xw1) : "v"(XQ[2]), "v"(XQ[3])); \
            asm("v_cvt_pk_bf16_f32 %0, %1, %2" : "=v"(xw2) : "v"(XQ[4]), "v"(XQ[5])); \
            asm("v_cvt_pk_bf16_f32 %0, %1, %2" : "=v"(xw3) : "v"(XQ[6]), "v"(XQ[7])); \
            if (t + 4 < T_STEPS) XQ = *(const f32x8*)(xrow + (t + 4) * 16); \
            u32x4 s1u = *(const u32x4*)&S1; \
            s1u[0] = usex ? xw0 : s1u[0]; \
            s1u[1] = usex ? xw1 : s1u[1]; \
            s1u[2] = usex ? xw2 : s1u[2]; \
            s1u[3] = usex ? xw3 : s1u[3]; \
            S1 = *(const bf16x8*)&s1u; \
            f32x4 c0 = __builtin_amdgcn_mfma_f32_16x16x32_bf16(F00, S0, BB0, 0, 0, 0); \
            MF(F01, S1, c0); \
            f32x4 c1 = __builtin_amdgcn_mfma_f32_16x16x32_bf16(F10, S0, BB1, 0, 0, 0); \
            MF(F11, S1, c1); \
            { GMATH(c0, hA0); Sb[(1 - (RP)) * PP + wof + 0] = bf16_cvt(hA0); } \
            { GMATH(c1, hA1); Sb[(1 - (RP)) * PP + wof + 4] = bf16_cvt(hA1); } \
            if (NTIL == 3) { \
                f32x4 c2 = __builtin_amdgcn_mfma_f32_16x16x32_bf16(F20, S0, BB2, 0, 0, 0); \
                MF(F21, S1, c2); \
                GMATH(c2, hA2); Sb[(1 - (RP)) * PP + wof + 8] = bf16_cvt(hA2); \
            } \
        } \
    } else { \
        const bf16x8 S0 = *(const bf16x8*)(Sb + r0p##RP); \
        const bf16x8 S1 = *(const bf16x8*)(Sb + r1p##RP); \
        const bf16x8 S2 = *(const bf16x8*)(Sb + r2p##RP); \
        f32x4 c0 = __builtin_amdgcn_mfma_f32_16x16x32_bf16(F00, S0, BB0, 0, 0, 0); \
        MF(F01, S1, c0); MF(F02, S2, c0); \
        f32x4 c1 = __builtin_amdgcn_mfma_f32_16x16x32_bf16(F10, S0, BB1, 0, 0, 0); \
        MF(F11, S1, c1); MF(F12, S2, c1); \
        if (t > 0) { \
            { GMATH(c0, hA0); Sb[(1 - (RP)) * PP + wof + 0] = bf16_cvt(hA0); } \
            { GMATH(c1, hA1); Sb[(1 - (RP)) * PP + wof + 4] = bf16_cvt(hA1); } \
        } \
        if (NTIL == 3) { \
            f32x4 c2 = __builtin_amdgcn_mfma_f32_16x16x32_bf16(F20, S0, BB2, 0, 0, 0); \
            MF(F21, S1, c2); MF(F22, S2, c2); \
            if (t > 0) { GMATH(c2, hA2); Sb[(1 - (RP)) * PP + wof + 8] = bf16_cvt(hA2); } \
        } \
    } \
    ++t; \
    __syncthreads(); }

    int t = 0;
    #pragma unroll 1
    for (int it = 0; it < 64; ++it) {
        BODY(0, XA)
        BODY(1, XB)
        BODY(0, XC)
        BODY(1, XD)
    }
    BODY(0, XA)   // t = 256: L1 finishes h1[255]; L0 inactive

    // ---- h1[255] straight from registers (4 L1 waves x 10 tiles x 4 units) ----
    if (isL1) {
        float* op = out + (size_t)(e0 + col) * HID + 4 * Tb + qrow;
        op[0] = hA0;
        op[4] = hA1;
        if (NTIL == 3) op[8] = hA2;
    }
}

extern "C" void kernel_launch(void* const* d_in, const int* in_sizes, int n_in,
                              void* d_out, int out_size, void* d_ws, size_t ws_size,
                              hipStream_t stream) {
    const float* x    = (const float*)d_in[0];
    const float* Wih0 = (const float*)d_in[1];
    const float* Whh0 = (const float*)d_in[2];
    const float* bih0 = (const float*)d_in[3];
    const float* bhh0 = (const float*)d_in[4];
    const float* Wih1 = (const float*)d_in[5];
    const float* Whh1 = (const float*)d_in[6];
    const float* bih1 = (const float*)d_in[7];
    const float* bhh1 = (const float*)d_in[8];
    float* out = (float*)d_out;

    dim3 grid(4096 / EPB), block(NTHR);
    hipLaunchKernelGGL(gru2_kernel, grid, block, 0, stream,
                       x, Wih0, Whh0, bih0, bhh0, Wih1, Whh1, bih1, bhh1, out);
}